// Round 13
// baseline (686.750 us; speedup 1.0000x reference)
//
#include <hip/hip_runtime.h>

#define K_DIM 8192
#define M_OUT 1024
#define N_OUT 4096
#define BUFSZ 65536   // single LDS buffer: A 32 KiB + B 32 KiB -> 2 blocks/CU

typedef __attribute__((ext_vector_type(4))) float f32x4;
typedef __attribute__((ext_vector_type(8))) __bf16 bf16x8;
typedef __attribute__((ext_vector_type(2))) __bf16 bf16x2;
typedef __attribute__((ext_vector_type(4))) unsigned u32x4;
typedef __attribute__((ext_vector_type(8))) unsigned short u16x8;

__device__ __forceinline__ unsigned short f2bf(float x) {
  unsigned u = __builtin_bit_cast(unsigned, x);
  u += 0x7fffu + ((u >> 16) & 1u);   // round-to-nearest-even
  return (unsigned short)(u >> 16);
}

__device__ __forceinline__ unsigned pack2(float a, float b) {
  bf16x2 v;
  v[0] = (__bf16)a;   // RNE; pairs lower to v_cvt_pk_bf16_f32
  v[1] = (__bf16)b;
  return __builtin_bit_cast(unsigned, v);
}

__device__ __forceinline__ float bf2f(unsigned short h) {
  unsigned u = ((unsigned)h) << 16;
  return __builtin_bit_cast(float, u);
}

// ---------------------------------------------------------------------------
// Pass 1: Cm[p][k] = bf16( cos(pi*(2P[p]+1)*k/16384) * w[k] * D[k] )
// ---------------------------------------------------------------------------
__global__ __launch_bounds__(256) void build_c_kernel(
    const int* __restrict__ Pp, const float* __restrict__ Dp,
    unsigned short* __restrict__ Cm) {
  const int p = blockIdx.x;
  const int n2 = 2 * Pp[p] + 1;
  const int t = threadIdx.x;
#pragma unroll
  for (int ch = 0; ch < 4; ++ch) {
    const int kb = (ch << 11) + (t << 3);
    u16x8 o;
#pragma unroll
    for (int i = 0; i < 8; ++i) {
      const int k = kb + i;
      const unsigned tt = ((unsigned)(n2 * k)) & 32767u;
      const float cv = cosf((float)tt * 1.9174759848570515e-4f);  // pi/16384
      const float wk = (k == 0) ? (0.5f / 8192.0f) : (1.0f / 8192.0f);
      o[i] = f2bf(cv * wk * Dp[k]);
    }
    *(u16x8*)(Cm + ((size_t)p << 13) + kb) = o;
  }
}

// ---------------------------------------------------------------------------
// Pass 2: GEMM  part[bz] = Cm[1024x8192] @ M  (B = M consumed directly, f32)
// BM=BN=256, BK=64, 512 thr (2Mx4N waves).  SINGLE-buffered LDS (64 KiB) ->
// 2 independent blocks/CU; m114 cross-block overlap replaces double-buffer.
// All maps identical to the R12-verified kernel.
// ---------------------------------------------------------------------------
__global__ __launch_bounds__(512, 4) void gemm_kernel(
    const unsigned short* __restrict__ Cm, const float* __restrict__ Mp,
    float* __restrict__ outf, unsigned short* __restrict__ outh,
    int kchunk, int nwg, int ksplit) {
  __shared__ __align__(16) char lds[BUFSZ];

  // XCD-aware bijective swizzle; (bz,bm) fastest so the blocks sharing a B
  // panel (same bn) are concentrated per XCD chunk.
  const int id = blockIdx.x;
  const int chunk = nwg >> 3;
  const int sid = (id & 7) * chunk + (id >> 3);
  const int bz = sid % ksplit;
  const int rest = sid / ksplit;
  const int bm = rest & 3, bn = rest >> 2;

  const int t = threadIdx.x;
  const int w = t >> 6, l = t & 63;
  const int wr = w >> 2, wc = w & 3;
  const int lg = l >> 4, lr = l & 15;
  const int k_begin = bz * kchunk;
  const int NT = kchunk >> 6;

  // ---- A staging: global_load_lds, source col pre-swizzled (LDS linear)
  const int arow = t >> 3;
  const int acol = ((t & 7) << 4) ^ ((arow & 7) << 4);
  const char* Agl = (const char*)Cm + ((size_t)(bm * 256 + arow) << 14) +
                    ((size_t)k_begin << 1) + acol;
  auto stageA = [&](int tile) {
    char* d = (char*)lds + t * 16;
    const char* s = Agl + ((size_t)tile << 7);
#pragma unroll
    for (int i = 0; i < 4; ++i)
      __builtin_amdgcn_global_load_lds(
          (const __attribute__((address_space(1))) void*)(s + ((size_t)i << 20)),
          (__attribute__((address_space(3))) void*)(d + i * 8192), 16, 0, 0);
  };

  // ---- B staging: thread t handles k = w*8 + (0..7), n = (t&63)*4 + nn
  const float* Bg = Mp + (size_t)k_begin * N_OUT + bn * 256 + l * 4;
  auto loadB = [&](f32x4 (&r)[8], int tile) {
#pragma unroll
    for (int i = 0; i < 8; ++i)
      r[i] = *(const f32x4*)(Bg + (size_t)(tile * 64 + w * 8 + i) * N_OUT);
  };
  auto writeB = [&](const f32x4 (&r)[8]) {
#pragma unroll
    for (int nn = 0; nn < 4; ++nn) {
      const int n = (l << 2) + nn;
      const int sN = (n & 7) ^ ((n >> 2) & 7);
      u32x4 pk;
#pragma unroll
      for (int j = 0; j < 4; ++j) pk[j] = pack2(r[2 * j][nn], r[2 * j + 1][nn]);
      *(u32x4*)(lds + 32768 + n * 128 + ((w ^ sN) << 4)) = pk;
    }
  };

  // ---- fragment read offsets
  const int sw = (lr & 7) << 4;
  const int xk0 = (lg << 4) ^ sw;
  const int xk1 = (64 + (lg << 4)) ^ sw;
  unsigned boff[2][4];
#pragma unroll
  for (int kk = 0; kk < 2; ++kk)
#pragma unroll
    for (int nf = 0; nf < 4; ++nf) {
      const int row = wc * 64 + nf * 16 + lr;
      const int sN = (row & 7) ^ ((row >> 2) & 7);
      boff[kk][nf] = 32768 + row * 128 + ((((kk << 2) | lg) ^ sN) << 4);
    }

  f32x4 acc[8][4] = {};
  bf16x8 Af[4];
  bf16x8 Bf[4];

  auto readA = [&](int mh, int xk) {
    const char* aBuf = (const char*)lds + wr * 16384 + lr * 128;
#pragma unroll
    for (int m = 0; m < 4; ++m)
      Af[m] = *(const bf16x8*)(aBuf + mh * 8192 + m * 2048 + xk);
  };
  auto readB = [&](int kk) {
#pragma unroll
    for (int nf = 0; nf < 4; ++nf)
      Bf[nf] = *(const bf16x8*)(lds + boff[kk][nf]);
  };
  auto mm = [&](int mh) {
    __builtin_amdgcn_s_setprio(1);
#pragma unroll
    for (int m = 0; m < 4; ++m)
#pragma unroll
      for (int nf = 0; nf < 4; ++nf)
        acc[mh * 4 + m][nf] = __builtin_amdgcn_mfma_f32_16x16x32_bf16(
            Af[m], Bf[nf], acc[mh * 4 + m][nf], 0, 0, 0);
    __builtin_amdgcn_s_setprio(0);
  };

  for (int tt = 0; tt < NT; ++tt) {
    // ---- stage phase (serial within block; co-resident block overlaps it)
    {
      f32x4 p[8];
      loadB(p, tt);
      stageA(tt);
      writeB(p);   // compiler waits vmcnt for p before the ds_writes
      asm volatile("s_waitcnt vmcnt(0) lgkmcnt(0)" ::: "memory");
      __builtin_amdgcn_sched_barrier(0);
      __builtin_amdgcn_s_barrier();
    }
    // ---- compute phase
    readB(0);
    readA(0, xk0);
    mm(0);
    readA(1, xk0);
    mm(1);
    readB(1);
    readA(0, xk1);
    mm(0);
    readA(1, xk1);
    mm(1);
    asm volatile("s_waitcnt lgkmcnt(0)" ::: "memory");
    __builtin_amdgcn_sched_barrier(0);
    __builtin_amdgcn_s_barrier();   // protect LDS from next tile's stage
  }

  // ---- epilogue
  const int orow = bm * 256 + wr * 128;
  const int ocol = bn * 256 + wc * 64 + lr;
  if (outh) {
    unsigned short* po = outh + (size_t)bz * (M_OUT * N_OUT);
#pragma unroll
    for (int mi = 0; mi < 8; ++mi) {
      const int r0 = orow + (mi >> 2) * 64 + (mi & 3) * 16 + (lg << 2);
#pragma unroll
      for (int ni = 0; ni < 4; ++ni) {
        const int c = ocol + ni * 16;
#pragma unroll
        for (int q = 0; q < 4; ++q)
          po[(size_t)(r0 + q) * N_OUT + c] = f2bf(acc[mi][ni][q]);
      }
    }
  } else {
#pragma unroll
    for (int mi = 0; mi < 8; ++mi) {
      const int r0 = orow + (mi >> 2) * 64 + (mi & 3) * 16 + (lg << 2);
#pragma unroll
      for (int ni = 0; ni < 4; ++ni) {
        const int c = ocol + ni * 16;
#pragma unroll
        for (int q = 0; q < 4; ++q)
          outf[(size_t)(r0 + q) * N_OUT + c] = acc[mi][ni][q];
      }
    }
  }
}

// ---------------------------------------------------------------------------
// Pass 3: reduce bf16 K-split partials -> f32 out
// ---------------------------------------------------------------------------
__global__ __launch_bounds__(256) void reduce_kernel(
    const unsigned short* __restrict__ part, float* __restrict__ out,
    int ksplit) {
  const size_t total = (size_t)M_OUT * N_OUT;
  const size_t i = ((size_t)blockIdx.x * 256 + threadIdx.x) * 8;
  if (i >= total) return;
  float s[8];
#pragma unroll
  for (int j = 0; j < 8; ++j) s[j] = 0.0f;
  for (int s2 = 0; s2 < ksplit; ++s2) {
    u16x8 v = *(const u16x8*)(part + (size_t)s2 * total + i);
#pragma unroll
    for (int j = 0; j < 8; ++j) s[j] += bf2f(v[j]);
  }
  f32x4 o0, o1;
#pragma unroll
  for (int j = 0; j < 4; ++j) { o0[j] = s[j]; o1[j] = s[4 + j]; }
  *(f32x4*)(out + i) = o0;
  *(f32x4*)(out + i + 4) = o1;
}

// ---------------------------------------------------------------------------
// Fallback: direct f32 evaluation
// ---------------------------------------------------------------------------
__global__ __launch_bounds__(256) void naive_kernel(
    const float* __restrict__ Mp, const float* __restrict__ Dp,
    const int* __restrict__ Pp, float* __restrict__ out) {
  const int p = blockIdx.y;
  const int j = blockIdx.x * 256 + threadIdx.x;
  const int n2 = 2 * Pp[p] + 1;
  float acc = 0.0f;
  for (int k = 0; k < K_DIM; ++k) {
    const unsigned tt = ((unsigned)(n2 * k)) & 32767u;
    const float cv = cosf((float)tt * 1.9174759848570515e-4f);
    const float wk = (k == 0) ? 0.5f : 1.0f;
    acc += cv * wk * Dp[k] * Mp[(size_t)k * N_OUT + j];
  }
  out[(size_t)p * N_OUT + j] = acc * (1.0f / 8192.0f);
}

extern "C" void kernel_launch(void* const* d_in, const int* in_sizes, int n_in,
                              void* d_out, int out_size, void* d_ws, size_t ws_size,
                              hipStream_t stream) {
  const float* Mp = (const float*)d_in[0];
  const float* Dp = (const float*)d_in[1];
  const int* Pp = (const int*)d_in[2];
  float* out = (float*)d_out;

  const size_t CM_BYTES = (size_t)M_OUT * K_DIM * 2;       // 16 MiB
  const size_t PART_BYTES = (size_t)M_OUT * N_OUT * 2;     // 8 MiB per split (bf16)

  int ksplit;
  if (ws_size >= CM_BYTES + 8 * PART_BYTES) ksplit = 8;
  else if (ws_size >= CM_BYTES + 4 * PART_BYTES) ksplit = 4;
  else if (ws_size >= CM_BYTES + 2 * PART_BYTES) ksplit = 2;
  else if (ws_size >= CM_BYTES) ksplit = 1;
  else ksplit = 0;

  if (ksplit == 0) {
    naive_kernel<<<dim3(N_OUT / 256, M_OUT), 256, 0, stream>>>(Mp, Dp, Pp, out);
    return;
  }

  unsigned short* Cm = (unsigned short*)d_ws;
  unsigned short* part = (unsigned short*)((char*)d_ws + CM_BYTES);

  build_c_kernel<<<dim3(M_OUT), 256, 0, stream>>>(Pp, Dp, Cm);

  const int kchunk = K_DIM / ksplit;
  const int nwg = 64 * ksplit;
  gemm_kernel<<<dim3(nwg), 512, 0, stream>>>(
      Cm, Mp, (ksplit > 1) ? nullptr : out, (ksplit > 1) ? part : nullptr,
      kchunk, nwg, ksplit);

  if (ksplit > 1)
    reduce_kernel<<<dim3((M_OUT * N_OUT / 8 + 255) / 256), 256, 0, stream>>>(
        part, out, ksplit);
}

// Round 14
// 187.309 us; speedup vs baseline: 3.6664x; 3.6664x over previous
//
#include <hip/hip_runtime.h>

#define K_DIM 8192
#define M_OUT 1024
#define N_OUT 4096
#define BBUF 32768   // per-dbuf LDS: B only, 32 KiB (A reads bypass LDS)

typedef __attribute__((ext_vector_type(4))) float f32x4;
typedef __attribute__((ext_vector_type(8))) __bf16 bf16x8;
typedef __attribute__((ext_vector_type(2))) __bf16 bf16x2;
typedef __attribute__((ext_vector_type(4))) unsigned u32x4;
typedef __attribute__((ext_vector_type(8))) unsigned short u16x8;

__device__ __forceinline__ unsigned short f2bf(float x) {
  unsigned u = __builtin_bit_cast(unsigned, x);
  u += 0x7fffu + ((u >> 16) & 1u);   // round-to-nearest-even
  return (unsigned short)(u >> 16);
}

__device__ __forceinline__ unsigned pack2(float a, float b) {
  bf16x2 v;
  v[0] = (__bf16)a;   // RNE; pairs lower to v_cvt_pk_bf16_f32
  v[1] = (__bf16)b;
  return __builtin_bit_cast(unsigned, v);
}

__device__ __forceinline__ float bf2f(unsigned short h) {
  unsigned u = ((unsigned)h) << 16;
  return __builtin_bit_cast(float, u);
}

// ---------------------------------------------------------------------------
// Pass 1: Cm[p][k] = bf16( cos(pi*(2P[p]+1)*k/16384) * w[k] * D[k] )
// ---------------------------------------------------------------------------
__global__ __launch_bounds__(256) void build_c_kernel(
    const int* __restrict__ Pp, const float* __restrict__ Dp,
    unsigned short* __restrict__ Cm) {
  const int p = blockIdx.x;
  const int n2 = 2 * Pp[p] + 1;
  const int t = threadIdx.x;
#pragma unroll
  for (int ch = 0; ch < 4; ++ch) {
    const int kb = (ch << 11) + (t << 3);
    u16x8 o;
#pragma unroll
    for (int i = 0; i < 8; ++i) {
      const int k = kb + i;
      const unsigned tt = ((unsigned)(n2 * k)) & 32767u;
      const float cv = cosf((float)tt * 1.9174759848570515e-4f);  // pi/16384
      const float wk = (k == 0) ? (0.5f / 8192.0f) : (1.0f / 8192.0f);
      o[i] = f2bf(cv * wk * Dp[k]);
    }
    *(u16x8*)(Cm + ((size_t)p << 13) + kb) = o;
  }
}

// ---------------------------------------------------------------------------
// Pass 2: GEMM  part[bz] = Cm[1024x8192] @ M.  BM=BN=256, BK=64, 512 thr
// (2Mx4N waves).  A: fragments loaded DIRECTLY global->VGPR (Cm is
// L2/L3-resident; each fragment = one aligned 16B load; no LDS, no barrier
// coupling).  B: R12-verified reg-stage f32 -> bf16 -> swizzled LDS dbuf.
// Tile barrier needs lgkmcnt(0) only — no vmcnt drain anywhere in the loop.
// ---------------------------------------------------------------------------
__global__ __launch_bounds__(512, 1) void gemm_kernel(
    const unsigned short* __restrict__ Cm, const float* __restrict__ Mp,
    float* __restrict__ outf, unsigned short* __restrict__ outh,
    int kchunk, int nwg, int ksplit) {
  __shared__ __align__(16) char lds[2 * BBUF];

  // XCD swizzle: bz fastest, bm slowest -> each XCD's chunk shares ONE 4 MiB
  // Cm panel (A re-reads stay in that XCD's L2).
  const int id = blockIdx.x;
  const int chunk = nwg >> 3;
  const int sid = (id & 7) * chunk + (id >> 3);
  const int bz = sid % ksplit;
  const int rest = sid / ksplit;
  const int bn = rest & 15, bm = rest >> 4;

  const int t = threadIdx.x;
  const int w = t >> 6, l = t & 63;
  const int wr = w >> 2, wc = w & 3;
  const int lg = l >> 4, lr = l & 15;
  const int k_begin = bz * kchunk;
  const int NT = kchunk >> 6;

  // ---- A: per-lane global fragment base (row = bm*256 + wr*128 + lr)
  const char* AglF = (const char*)Cm +
                     ((size_t)(bm * 256 + wr * 128 + lr) << 14) +
                     ((size_t)k_begin << 1) + (lg << 4);
  // fragment (tile, mh, m, kk): + tile*128 + kk*64 + (mh<<20) + (m<<18)

  // ---- B staging: thread t handles k = w*8 + (0..7), n = (t&63)*4 + nn
  const float* Bg = Mp + (size_t)k_begin * N_OUT + bn * 256 + l * 4;
  auto loadB = [&](f32x4 (&r)[8], int tile) {
#pragma unroll
    for (int i = 0; i < 8; ++i)
      r[i] = *(const f32x4*)(Bg + (size_t)(tile * 64 + w * 8 + i) * N_OUT);
  };
  auto writeB = [&](const f32x4 (&r)[8], int nbuf) {
#pragma unroll
    for (int nn = 0; nn < 4; ++nn) {
      const int n = (l << 2) + nn;
      const int sN = (n & 7) ^ ((n >> 2) & 7);
      u32x4 pk;
#pragma unroll
      for (int j = 0; j < 4; ++j) pk[j] = pack2(r[2 * j][nn], r[2 * j + 1][nn]);
      *(u32x4*)(lds + nbuf * BBUF + n * 128 + ((w ^ sN) << 4)) = pk;
    }
  };

  // ---- B fragment read offsets (R12-verified)
  unsigned boff[2][4];
#pragma unroll
  for (int kk = 0; kk < 2; ++kk)
#pragma unroll
    for (int nf = 0; nf < 4; ++nf) {
      const int row = wc * 64 + nf * 16 + lr;
      const int sN = (row & 7) ^ ((row >> 2) & 7);
      boff[kk][nf] = row * 128 + ((((kk << 2) | lg) ^ sN) << 4);
    }

  f32x4 acc[8][4] = {};
  bf16x8 Af0[4], Af1[4];
  bf16x8 Bf[4];

  auto gloadA = [&](bf16x8 (&Afr)[4], int tile, int mh, int kk) {
    const char* p = AglF + ((size_t)tile << 7) + (kk << 6) + ((size_t)mh << 20);
#pragma unroll
    for (int m = 0; m < 4; ++m)
      Afr[m] = *(const bf16x8*)(p + ((size_t)m << 18));
  };
  auto readB = [&](int nbuf, int kk) {
#pragma unroll
    for (int nf = 0; nf < 4; ++nf)
      Bf[nf] = *(const bf16x8*)(lds + nbuf * BBUF + boff[kk][nf]);
  };
  auto mm = [&](int mh, const bf16x8 (&Afr)[4]) {
    __builtin_amdgcn_s_setprio(1);
#pragma unroll
    for (int m = 0; m < 4; ++m)
#pragma unroll
      for (int nf = 0; nf < 4; ++nf)
        acc[mh * 4 + m][nf] = __builtin_amdgcn_mfma_f32_16x16x32_bf16(
            Afr[m], Bf[nf], acc[mh * 4 + m][nf], 0, 0, 0);
    __builtin_amdgcn_s_setprio(0);
  };

  // ---- prologue: B tile 0 -> buf 0
  {
    f32x4 p[8];
    loadB(p, 0);
    writeB(p, 0);   // compiler waits vmcnt for p before the ds_writes
    asm volatile("s_waitcnt lgkmcnt(0)" ::: "memory");
    __builtin_amdgcn_sched_barrier(0);
    __builtin_amdgcn_s_barrier();
  }

  for (int tt = 0; tt < NT; ++tt) {
    const int cur = tt & 1, nxt = cur ^ 1;
    const bool more = (tt + 1) < NT;
    f32x4 sb[8];
    if (more) loadB(sb, tt + 1);
    // kk0
    gloadA(Af0, tt, 0, 0);
    gloadA(Af1, tt, 1, 0);
    readB(cur, 0);
    mm(0, Af0);
    mm(1, Af1);
    if (more) writeB(sb, nxt);
    // kk1
    gloadA(Af0, tt, 0, 1);
    gloadA(Af1, tt, 1, 1);
    readB(cur, 1);
    mm(0, Af0);
    mm(1, Af1);
    // barrier protects the B double-buffer only: DS ops must be done; no
    // vmcnt drain (A waits handled per-consumer by the compiler).
    asm volatile("s_waitcnt lgkmcnt(0)" ::: "memory");
    __builtin_amdgcn_sched_barrier(0);
    __builtin_amdgcn_s_barrier();
  }

  // ---- epilogue (R12-verified)
  const int orow = bm * 256 + wr * 128;
  const int ocol = bn * 256 + wc * 64 + lr;
  if (outh) {
    unsigned short* po = outh + (size_t)bz * (M_OUT * N_OUT);
#pragma unroll
    for (int mi = 0; mi < 8; ++mi) {
      const int r0 = orow + (mi >> 2) * 64 + (mi & 3) * 16 + (lg << 2);
#pragma unroll
      for (int ni = 0; ni < 4; ++ni) {
        const int c = ocol + ni * 16;
#pragma unroll
        for (int q = 0; q < 4; ++q)
          po[(size_t)(r0 + q) * N_OUT + c] = f2bf(acc[mi][ni][q]);
      }
    }
  } else {
#pragma unroll
    for (int mi = 0; mi < 8; ++mi) {
      const int r0 = orow + (mi >> 2) * 64 + (mi & 3) * 16 + (lg << 2);
#pragma unroll
      for (int ni = 0; ni < 4; ++ni) {
        const int c = ocol + ni * 16;
#pragma unroll
        for (int q = 0; q < 4; ++q)
          outf[(size_t)(r0 + q) * N_OUT + c] = acc[mi][ni][q];
      }
    }
  }
}

// ---------------------------------------------------------------------------
// Pass 3: reduce bf16 K-split partials -> f32 out
// ---------------------------------------------------------------------------
__global__ __launch_bounds__(256) void reduce_kernel(
    const unsigned short* __restrict__ part, float* __restrict__ out,
    int ksplit) {
  const size_t total = (size_t)M_OUT * N_OUT;
  const size_t i = ((size_t)blockIdx.x * 256 + threadIdx.x) * 8;
  if (i >= total) return;
  float s[8];
#pragma unroll
  for (int j = 0; j < 8; ++j) s[j] = 0.0f;
  for (int s2 = 0; s2 < ksplit; ++s2) {
    u16x8 v = *(const u16x8*)(part + (size_t)s2 * total + i);
#pragma unroll
    for (int j = 0; j < 8; ++j) s[j] += bf2f(v[j]);
  }
  f32x4 o0, o1;
#pragma unroll
  for (int j = 0; j < 4; ++j) { o0[j] = s[j]; o1[j] = s[4 + j]; }
  *(f32x4*)(out + i) = o0;
  *(f32x4*)(out + i + 4) = o1;
}

// ---------------------------------------------------------------------------
// Fallback: direct f32 evaluation
// ---------------------------------------------------------------------------
__global__ __launch_bounds__(256) void naive_kernel(
    const float* __restrict__ Mp, const float* __restrict__ Dp,
    const int* __restrict__ Pp, float* __restrict__ out) {
  const int p = blockIdx.y;
  const int j = blockIdx.x * 256 + threadIdx.x;
  const int n2 = 2 * Pp[p] + 1;
  float acc = 0.0f;
  for (int k = 0; k < K_DIM; ++k) {
    const unsigned tt = ((unsigned)(n2 * k)) & 32767u;
    const float cv = cosf((float)tt * 1.9174759848570515e-4f);
    const float wk = (k == 0) ? 0.5f : 1.0f;
    acc += cv * wk * Dp[k] * Mp[(size_t)k * N_OUT + j];
  }
  out[(size_t)p * N_OUT + j] = acc * (1.0f / 8192.0f);
}

extern "C" void kernel_launch(void* const* d_in, const int* in_sizes, int n_in,
                              void* d_out, int out_size, void* d_ws, size_t ws_size,
                              hipStream_t stream) {
  const float* Mp = (const float*)d_in[0];
  const float* Dp = (const float*)d_in[1];
  const int* Pp = (const int*)d_in[2];
  float* out = (float*)d_out;

  const size_t CM_BYTES = (size_t)M_OUT * K_DIM * 2;       // 16 MiB
  const size_t PART_BYTES = (size_t)M_OUT * N_OUT * 2;     // 8 MiB per split (bf16)

  int ksplit;
  if (ws_size >= CM_BYTES + 4 * PART_BYTES) ksplit = 4;
  else if (ws_size >= CM_BYTES + 2 * PART_BYTES) ksplit = 2;
  else if (ws_size >= CM_BYTES) ksplit = 1;
  else ksplit = 0;

  if (ksplit == 0) {
    naive_kernel<<<dim3(N_OUT / 256, M_OUT), 256, 0, stream>>>(Mp, Dp, Pp, out);
    return;
  }

  unsigned short* Cm = (unsigned short*)d_ws;
  unsigned short* part = (unsigned short*)((char*)d_ws + CM_BYTES);

  build_c_kernel<<<dim3(M_OUT), 256, 0, stream>>>(Pp, Dp, Cm);

  const int kchunk = K_DIM / ksplit;
  const int nwg = 64 * ksplit;
  gemm_kernel<<<dim3(nwg), 512, 0, stream>>>(
      Cm, Mp, (ksplit > 1) ? nullptr : out, (ksplit > 1) ? part : nullptr,
      kchunk, nwg, ksplit);

  if (ksplit > 1)
    reduce_kernel<<<dim3((M_OUT * N_OUT / 8 + 255) / 256), 256, 0, stream>>>(
        part, out, ksplit);
}

// Round 15
// 102.372 us; speedup vs baseline: 6.7084x; 1.8297x over previous
//
#include <hip/hip_runtime.h>

#define K_DIM 8192
#define M_OUT 1024
#define N_OUT 4096
#define BUFSZ 65536   // per-dbuf LDS: A 32 KiB + B 32 KiB

typedef __attribute__((ext_vector_type(4))) float f32x4;
typedef __attribute__((ext_vector_type(8))) __bf16 bf16x8;
typedef __attribute__((ext_vector_type(2))) __bf16 bf16x2;
typedef __attribute__((ext_vector_type(4))) unsigned u32x4;
typedef __attribute__((ext_vector_type(8))) unsigned short u16x8;

__device__ __forceinline__ unsigned short f2bf(float x) {
  unsigned u = __builtin_bit_cast(unsigned, x);
  u += 0x7fffu + ((u >> 16) & 1u);   // round-to-nearest-even
  return (unsigned short)(u >> 16);
}

__device__ __forceinline__ unsigned pack2(float a, float b) {
  bf16x2 v;
  v[0] = (__bf16)a;   // RNE; pairs lower to v_cvt_pk_bf16_f32
  v[1] = (__bf16)b;
  return __builtin_bit_cast(unsigned, v);
}

__device__ __forceinline__ float bf2f(unsigned short h) {
  unsigned u = ((unsigned)h) << 16;
  return __builtin_bit_cast(float, u);
}

// ---------------------------------------------------------------------------
// Pass 1: Cm[p][k] = bf16( cos(pi*(2P[p]+1)*k/16384) * w[k] * D[k] )
// ---------------------------------------------------------------------------
__global__ __launch_bounds__(256) void build_c_kernel(
    const int* __restrict__ Pp, const float* __restrict__ Dp,
    unsigned short* __restrict__ Cm) {
  const int p = blockIdx.x;
  const int n2 = 2 * Pp[p] + 1;
  const int t = threadIdx.x;
#pragma unroll
  for (int ch = 0; ch < 4; ++ch) {
    const int kb = (ch << 11) + (t << 3);
    u16x8 o;
#pragma unroll
    for (int i = 0; i < 8; ++i) {
      const int k = kb + i;
      const unsigned tt = ((unsigned)(n2 * k)) & 32767u;
      const float cv = cosf((float)tt * 1.9174759848570515e-4f);  // pi/16384
      const float wk = (k == 0) ? (0.5f / 8192.0f) : (1.0f / 8192.0f);
      o[i] = f2bf(cv * wk * Dp[k]);
    }
    *(u16x8*)(Cm + ((size_t)p << 13) + kb) = o;
  }
}

// ---------------------------------------------------------------------------
// Pass 2: GEMM  part[bz] = Cm[1024x8192] @ M  (B = M consumed directly, f32)
// BM=BN=256, BK=64, 512 thr (2Mx4N waves).  R6-verified loop (drain-0).
// Epilogue: bf16 partials when ksplit>1 (halves reduce traffic), f32 direct
// when ksplit==1.
// ---------------------------------------------------------------------------
__global__ __launch_bounds__(512, 1) void gemm_kernel(
    const unsigned short* __restrict__ Cm, const float* __restrict__ Mp,
    float* __restrict__ outf, unsigned short* __restrict__ outh,
    int kchunk, int nwg) {
  __shared__ __align__(16) char lds[2 * BUFSZ];

  // XCD-aware bijective swizzle; bm-major so each XCD chunk reuses B panels
  const int id = blockIdx.x;
  const int chunk = nwg >> 3;
  const int sid = (id & 7) * chunk + (id >> 3);
  const int bm = sid & 3, bn = (sid >> 2) & 15, bz = sid >> 6;

  const int t = threadIdx.x;
  const int w = t >> 6, l = t & 63;
  const int wr = w >> 2, wc = w & 3;
  const int lg = l >> 4, lr = l & 15;
  const int k_begin = bz * kchunk;
  const int NT = kchunk >> 6;

  // ---- A staging: global_load_lds, source col pre-swizzled (LDS linear)
  const int arow = t >> 3;
  const int acol = ((t & 7) << 4) ^ ((arow & 7) << 4);
  const char* Agl = (const char*)Cm + ((size_t)(bm * 256 + arow) << 14) +
                    ((size_t)k_begin << 1) + acol;
  auto stageA = [&](int nbuf, int tile) {
    char* d = (char*)lds + nbuf * BUFSZ + t * 16;
    const char* s = Agl + ((size_t)tile << 7);
#pragma unroll
    for (int i = 0; i < 4; ++i)
      __builtin_amdgcn_global_load_lds(
          (const __attribute__((address_space(1))) void*)(s + ((size_t)i << 20)),
          (__attribute__((address_space(3))) void*)(d + i * 8192), 16, 0, 0);
  };

  // ---- B staging: thread t handles k = w*8 + (0..7), n = (t&63)*4 + nn
  const float* Bg = Mp + (size_t)k_begin * N_OUT + bn * 256 + l * 4;
  auto loadB = [&](f32x4 (&r)[8], int tile, int half) {
#pragma unroll
    for (int i = 0; i < 4; ++i)
      r[half * 4 + i] =
          *(const f32x4*)(Bg + (size_t)(tile * 64 + w * 8 + half * 4 + i) * N_OUT);
  };
  auto writeB = [&](const f32x4 (&r)[8], int nbuf, int nn) {
    const int n = (l << 2) + nn;
    const int sN = (n & 7) ^ ((n >> 2) & 7);
    u32x4 pk;
#pragma unroll
    for (int j = 0; j < 4; ++j) pk[j] = pack2(r[2 * j][nn], r[2 * j + 1][nn]);
    *(u32x4*)(lds + nbuf * BUFSZ + 32768 + n * 128 + ((w ^ sN) << 4)) = pk;
  };

  // ---- fragment read offsets
  const int sw = (lr & 7) << 4;
  const int xk0 = (lg << 4) ^ sw;
  const int xk1 = (64 + (lg << 4)) ^ sw;
  unsigned boff[2][4];
#pragma unroll
  for (int kk = 0; kk < 2; ++kk)
#pragma unroll
    for (int nf = 0; nf < 4; ++nf) {
      const int row = wc * 64 + nf * 16 + lr;
      const int sN = (row & 7) ^ ((row >> 2) & 7);
      boff[kk][nf] = 32768 + row * 128 + ((((kk << 2) | lg) ^ sN) << 4);
    }

  f32x4 acc[8][4] = {};
  bf16x8 Af[4];
  bf16x8 Bf[4];

  auto readA = [&](const char* aBuf, int mh, int xk) {
#pragma unroll
    for (int m = 0; m < 4; ++m)
      Af[m] = *(const bf16x8*)(aBuf + mh * 8192 + m * 2048 + xk);
  };
  auto readB = [&](int nbuf, int kk) {
#pragma unroll
    for (int nf = 0; nf < 4; ++nf)
      Bf[nf] = *(const bf16x8*)(lds + nbuf * BUFSZ + boff[kk][nf]);
  };
  auto mm = [&](int mh) {
    __builtin_amdgcn_s_setprio(1);
#pragma unroll
    for (int m = 0; m < 4; ++m)
#pragma unroll
      for (int nf = 0; nf < 4; ++nf)
        acc[mh * 4 + m][nf] = __builtin_amdgcn_mfma_f32_16x16x32_bf16(
            Af[m], Bf[nf], acc[mh * 4 + m][nf], 0, 0, 0);
    __builtin_amdgcn_s_setprio(0);
  };

  // ---- prologue: tile 0 into buf 0
  {
    f32x4 p[8];
    stageA(0, 0);
    loadB(p, 0, 0);
    loadB(p, 0, 1);
#pragma unroll
    for (int nn = 0; nn < 4; ++nn) writeB(p, 0, nn);
    asm volatile("s_waitcnt vmcnt(0) lgkmcnt(0)" ::: "memory");
    __builtin_amdgcn_sched_barrier(0);
    __builtin_amdgcn_s_barrier();
  }

  for (int tt = 0; tt < NT; ++tt) {
    const int cur = tt & 1, nxt = cur ^ 1;
    const char* aBuf = (const char*)lds + cur * BUFSZ + wr * 16384 + lr * 128;
    const bool more = (tt + 1) < NT;
    f32x4 sb[8];
    if (more) {
      loadB(sb, tt + 1, 0);
      loadB(sb, tt + 1, 1);
      stageA(nxt, tt + 1);
    }
    // kk0
    readB(cur, 0);
    readA(aBuf, 0, xk0);
    mm(0);
    readA(aBuf, 1, xk0);
    mm(1);
    if (more) {
      writeB(sb, nxt, 0);
      writeB(sb, nxt, 1);
      writeB(sb, nxt, 2);
      writeB(sb, nxt, 3);
    }
    // kk1
    readB(cur, 1);
    readA(aBuf, 0, xk1);
    mm(0);
    readA(aBuf, 1, xk1);
    mm(1);
    asm volatile("s_waitcnt vmcnt(0) lgkmcnt(0)" ::: "memory");
    __builtin_amdgcn_sched_barrier(0);
    __builtin_amdgcn_s_barrier();
  }

  // ---- epilogue
  const int orow = bm * 256 + wr * 128;
  const int ocol = bn * 256 + wc * 64 + lr;
  if (outh) {
    unsigned short* po = outh + (size_t)bz * (M_OUT * N_OUT);
#pragma unroll
    for (int mi = 0; mi < 8; ++mi) {
      const int r0 = orow + (mi >> 2) * 64 + (mi & 3) * 16 + (lg << 2);
#pragma unroll
      for (int ni = 0; ni < 4; ++ni) {
        const int c = ocol + ni * 16;
#pragma unroll
        for (int q = 0; q < 4; ++q)
          po[(size_t)(r0 + q) * N_OUT + c] = f2bf(acc[mi][ni][q]);
      }
    }
  } else {
#pragma unroll
    for (int mi = 0; mi < 8; ++mi) {
      const int r0 = orow + (mi >> 2) * 64 + (mi & 3) * 16 + (lg << 2);
#pragma unroll
      for (int ni = 0; ni < 4; ++ni) {
        const int c = ocol + ni * 16;
#pragma unroll
        for (int q = 0; q < 4; ++q)
          outf[(size_t)(r0 + q) * N_OUT + c] = acc[mi][ni][q];
      }
    }
  }
}

// ---------------------------------------------------------------------------
// Pass 3: reduce bf16 K-split partials -> f32 out
// ---------------------------------------------------------------------------
__global__ __launch_bounds__(256) void reduce_kernel(
    const unsigned short* __restrict__ part, float* __restrict__ out,
    int ksplit) {
  const size_t total = (size_t)M_OUT * N_OUT;
  const size_t i = ((size_t)blockIdx.x * 256 + threadIdx.x) * 8;
  if (i >= total) return;
  float s[8];
#pragma unroll
  for (int j = 0; j < 8; ++j) s[j] = 0.0f;
  for (int s2 = 0; s2 < ksplit; ++s2) {
    u16x8 v = *(const u16x8*)(part + (size_t)s2 * total + i);
#pragma unroll
    for (int j = 0; j < 8; ++j) s[j] += bf2f(v[j]);
  }
  f32x4 o0, o1;
#pragma unroll
  for (int j = 0; j < 4; ++j) { o0[j] = s[j]; o1[j] = s[4 + j]; }
  *(f32x4*)(out + i) = o0;
  *(f32x4*)(out + i + 4) = o1;
}

// ---------------------------------------------------------------------------
// Fallback: direct f32 evaluation
// ---------------------------------------------------------------------------
__global__ __launch_bounds__(256) void naive_kernel(
    const float* __restrict__ Mp, const float* __restrict__ Dp,
    const int* __restrict__ Pp, float* __restrict__ out) {
  const int p = blockIdx.y;
  const int j = blockIdx.x * 256 + threadIdx.x;
  const int n2 = 2 * Pp[p] + 1;
  float acc = 0.0f;
  for (int k = 0; k < K_DIM; ++k) {
    const unsigned tt = ((unsigned)(n2 * k)) & 32767u;
    const float cv = cosf((float)tt * 1.9174759848570515e-4f);
    const float wk = (k == 0) ? 0.5f : 1.0f;
    acc += cv * wk * Dp[k] * Mp[(size_t)k * N_OUT + j];
  }
  out[(size_t)p * N_OUT + j] = acc * (1.0f / 8192.0f);
}

extern "C" void kernel_launch(void* const* d_in, const int* in_sizes, int n_in,
                              void* d_out, int out_size, void* d_ws, size_t ws_size,
                              hipStream_t stream) {
  const float* Mp = (const float*)d_in[0];
  const float* Dp = (const float*)d_in[1];
  const int* Pp = (const int*)d_in[2];
  float* out = (float*)d_out;

  const size_t CM_BYTES = (size_t)M_OUT * K_DIM * 2;       // 16 MiB
  const size_t PART_BYTES = (size_t)M_OUT * N_OUT * 2;     // 8 MiB per split (bf16)

  int ksplit;
  if (ws_size >= CM_BYTES + 4 * PART_BYTES) ksplit = 4;
  else if (ws_size >= CM_BYTES + 2 * PART_BYTES) ksplit = 2;
  else if (ws_size >= CM_BYTES) ksplit = 1;
  else ksplit = 0;

  if (ksplit == 0) {
    naive_kernel<<<dim3(N_OUT / 256, M_OUT), 256, 0, stream>>>(Mp, Dp, Pp, out);
    return;
  }

  unsigned short* Cm = (unsigned short*)d_ws;
  unsigned short* part = (unsigned short*)((char*)d_ws + CM_BYTES);

  build_c_kernel<<<dim3(M_OUT), 256, 0, stream>>>(Pp, Dp, Cm);

  const int kchunk = K_DIM / ksplit;
  const int nwg = 64 * ksplit;
  gemm_kernel<<<dim3(nwg), 512, 0, stream>>>(
      Cm, Mp, (ksplit > 1) ? nullptr : out, (ksplit > 1) ? part : nullptr,
      kchunk, nwg);

  if (ksplit > 1)
    reduce_kernel<<<dim3((M_OUT * N_OUT / 8 + 255) / 256), 256, 0, stream>>>(
        part, out, ksplit);
}